// Round 3
// baseline (2651.379 us; speedup 1.0000x reference)
//
#include <hip/hip_runtime.h>

typedef __bf16 bf16x8 __attribute__((ext_vector_type(8)));
typedef float  f32x4  __attribute__((ext_vector_type(4)));

static constexpr int M_TOK = 16384;       // B*S
static constexpr int D_IN  = 2048;
static constexpr int H_FF  = 5632;
static constexpr int NW    = H_FF * D_IN; // 11534336

// exact float->bf16 for exactly-representable values (ints in [-128,127], {-1,0,1})
__device__ __forceinline__ unsigned short f2bf(float f) {
    return (unsigned short)(__float_as_uint(f) >> 16);
}

__device__ __forceinline__ void async16(const void* g, void* l) {
    __builtin_amdgcn_global_load_lds((__attribute__((address_space(1))) void*)g,
                                     (__attribute__((address_space(3))) void*)l,
                                     16, 0, 0);
}

// ---------------- weight abs-mean reduction, FP64 accumulate ----------------
__global__ void absum_partial(const float4* __restrict__ w, int n4, double* __restrict__ part) {
    __shared__ double s[256];
    const int t = threadIdx.x;
    double acc = 0.0;
    for (int i = blockIdx.x * 256 + t; i < n4; i += gridDim.x * 256) {
        float4 v = w[i];
        acc += fabs((double)v.x) + fabs((double)v.y) + fabs((double)v.z) + fabs((double)v.w);
    }
    s[t] = acc;
    __syncthreads();
    for (int o = 128; o > 0; o >>= 1) {
        if (t < o) s[t] += s[t + o];
        __syncthreads();
    }
    if (t == 0) part[blockIdx.x] = s[0];
}

__global__ void finalize_scales(const double* __restrict__ parts, double* __restrict__ scales,
                                int nblocks, double inv_n) {
    const int t = threadIdx.x;
    if (t < 3) {
        const double* p = parts + t * nblocks;
        double s = 0.0;
        for (int i = 0; i < nblocks; ++i) s += p[i];
        double c = fmax(s * inv_n, 1e-5);   // clip(mean|w|, EPS)
        scales[t * 2]     = 1.0 / c;        // quantization scale (fp64)
        scales[t * 2 + 1] = c;              // dequant coeff (fp64)
    }
}

// ---------------- weight ternarization (FP64 rounding decision) -> bf16 {-1,0,1} ----------
__global__ void quant_w_kernel(const float4* __restrict__ w, ushort4* __restrict__ tw,
                               const double* __restrict__ scales, int idx, int n4) {
    const double s = scales[idx * 2];
    const int stride = gridDim.x * blockDim.x;
    for (int i = blockIdx.x * blockDim.x + threadIdx.x; i < n4; i += stride) {
        float4 v = w[i];
        ushort4 o;
        o.x = f2bf((float)fmin(fmax(rint((double)v.x * s), -1.0), 1.0));
        o.y = f2bf((float)fmin(fmax(rint((double)v.y * s), -1.0), 1.0));
        o.z = f2bf((float)fmin(fmax(rint((double)v.z * s), -1.0), 1.0));
        o.w = f2bf((float)fmin(fmax(rint((double)v.w * s), -1.0), 1.0));
        tw[i] = o;
    }
}

// ---------------- x: rmsnorm + int8 absmax quant, FP64 stats & rounding ----------------
__global__ void quant_x_kernel(const float* __restrict__ x, unsigned short* __restrict__ qx,
                               double* __restrict__ cx) {
    __shared__ double ssum[256];
    __shared__ float  smax[256];
    const int token = blockIdx.x;
    const int t = threadIdx.x;
    const float4* xr = (const float4*)(x + (size_t)token * D_IN);
    float4 v0 = xr[t];
    float4 v1 = xr[t + 256];
    double ss = (double)v0.x*v0.x + (double)v0.y*v0.y + (double)v0.z*v0.z + (double)v0.w*v0.w
              + (double)v1.x*v1.x + (double)v1.y*v1.y + (double)v1.z*v1.z + (double)v1.w*v1.w;
    float mx = fmaxf(fmaxf(fmaxf(fabsf(v0.x), fabsf(v0.y)), fmaxf(fabsf(v0.z), fabsf(v0.w))),
                     fmaxf(fmaxf(fabsf(v1.x), fabsf(v1.y)), fmaxf(fabsf(v1.z), fabsf(v1.w))));
    ssum[t] = ss; smax[t] = mx;
    __syncthreads();
    for (int o = 128; o > 0; o >>= 1) {
        if (t < o) { ssum[t] += ssum[t + o]; smax[t] = fmaxf(smax[t], smax[t + o]); }
        __syncthreads();
    }
    const double ms    = ssum[0] * (1.0 / (double)D_IN);
    const double r     = 1.0 / sqrt(ms + 1e-6);
    const double den   = fmax((double)smax[0] * r, 1e-5);   // clip(max|xn|, EPS)
    const double scale = 127.0 / den;
    if (t == 0) cx[token] = den * (1.0 / 127.0);

    ushort4* qr = (ushort4*)(qx + (size_t)token * D_IN);
    ushort4 o0, o1;
    o0.x = f2bf((float)fmin(fmax(rint(((double)v0.x * r) * scale), -128.0), 127.0));
    o0.y = f2bf((float)fmin(fmax(rint(((double)v0.y * r) * scale), -128.0), 127.0));
    o0.z = f2bf((float)fmin(fmax(rint(((double)v0.z * r) * scale), -128.0), 127.0));
    o0.w = f2bf((float)fmin(fmax(rint(((double)v0.w * r) * scale), -128.0), 127.0));
    o1.x = f2bf((float)fmin(fmax(rint(((double)v1.x * r) * scale), -128.0), 127.0));
    o1.y = f2bf((float)fmin(fmax(rint(((double)v1.y * r) * scale), -128.0), 127.0));
    o1.z = f2bf((float)fmin(fmax(rint(((double)v1.z * r) * scale), -128.0), 127.0));
    o1.w = f2bf((float)fmin(fmax(rint(((double)v1.w * r) * scale), -128.0), 127.0));
    qr[t] = o0;
    qr[t + 256] = o1;
}

// ---------------- h: rmsnorm + quant IN-PLACE per token, FP64 stats & rounding -------------
__global__ void quant_h_kernel(float* __restrict__ h, double* __restrict__ ch) {
    __shared__ double ssum[256];
    __shared__ float  smax[256];
    const int token = blockIdx.x;
    const int t = threadIdx.x;
    float* hr = h + (size_t)token * H_FF;
    float vals[22];                       // 5632 = 256*22
    double ss = 0.0;
    float mx = 0.f;
#pragma unroll
    for (int k = 0; k < 22; ++k) {
        float v = hr[t + 256 * k];
        vals[k] = v;
        ss += (double)v * (double)v;
        mx = fmaxf(mx, fabsf(v));
    }
    ssum[t] = ss; smax[t] = mx;
    __syncthreads();
    for (int o = 128; o > 0; o >>= 1) {
        if (t < o) { ssum[t] += ssum[t + o]; smax[t] = fmaxf(smax[t], smax[t + o]); }
        __syncthreads();
    }
    const double ms    = ssum[0] * (1.0 / (double)H_FF);
    const double r     = 1.0 / sqrt(ms + 1e-6);
    const double den   = fmax((double)smax[0] * r, 1e-5);
    const double scale = 127.0 / den;
    if (t == 0) ch[token] = den * (1.0 / 127.0);
    unsigned short* qr = (unsigned short*)hr;   // in-place overlay, same token row
#pragma unroll
    for (int k = 0; k < 22; ++k) {
        qr[t + 256 * k] =
            f2bf((float)fmin(fmax(rint(((double)vals[k] * r) * scale), -128.0), 127.0));
    }
}

// ---------------- fused GEMM1+2 (shared A, two B, silu(gate)*up -> fp32 h) ----------------
__global__ void __launch_bounds__(256) gemm12_kernel(
    const unsigned short* __restrict__ qx,
    const unsigned short* __restrict__ tw1,
    const unsigned short* __restrict__ tw2,
    const double* __restrict__ cx,
    const double* __restrict__ scales,
    float* __restrict__ h)
{
    __shared__ unsigned short ldsA[128 * 32];
    __shared__ unsigned short ldsB1[128 * 32];
    __shared__ unsigned short ldsB2[128 * 32];

    const int t  = threadIdx.x;
    const int bn = blockIdx.x;
    const int bm = blockIdx.y;

    const int srow = t >> 2;
    const int scol = (t & 3) << 3;
    const unsigned short* gA  = qx  + (size_t)(bm * 128 + srow) * D_IN + scol;
    const unsigned short* gB1 = tw1 + (size_t)(bn * 128 + srow) * D_IN + scol;
    const unsigned short* gB2 = tw2 + (size_t)(bn * 128 + srow) * D_IN + scol;
    const size_t rstep = (size_t)64 * D_IN;

    unsigned short* lA0  = &ldsA [t * 8];
    unsigned short* lA1  = &ldsA [(t + 256) * 8];
    unsigned short* lB10 = &ldsB1[t * 8];
    unsigned short* lB11 = &ldsB1[(t + 256) * 8];
    unsigned short* lB20 = &ldsB2[t * 8];
    unsigned short* lB21 = &ldsB2[(t + 256) * 8];

    const int lane = t & 63;
    const int wv = t >> 6;
    const int wm = wv & 1;
    const int wn = wv >> 1;
    const int lm = lane & 15;
    const int kg = lane >> 4;

    int aoff[4], boff[4];
#pragma unroll
    for (int i = 0; i < 4; ++i) aoff[i] = (wm * 64 + i * 16 + lm) * 32 + kg * 8;
#pragma unroll
    for (int j = 0; j < 4; ++j) boff[j] = (wn * 64 + j * 16 + lm) * 32 + kg * 8;

    const f32x4 fzero = {0.f, 0.f, 0.f, 0.f};
    f32x4 acc1[4][4], acc2[4][4];
#pragma unroll
    for (int i = 0; i < 4; ++i)
#pragma unroll
        for (int j = 0; j < 4; ++j) { acc1[i][j] = fzero; acc2[i][j] = fzero; }

    for (int kt = 0; kt < D_IN / 32; ++kt) {
        __syncthreads();
        const int go = kt * 32;
        async16(gA  + go, lA0);  async16(gA  + rstep + go, lA1);
        async16(gB1 + go, lB10); async16(gB1 + rstep + go, lB11);
        async16(gB2 + go, lB20); async16(gB2 + rstep + go, lB21);
        __syncthreads();

        bf16x8 a[4], b1[4], b2[4];
#pragma unroll
        for (int i = 0; i < 4; ++i) a[i] = *(const bf16x8*)&ldsA[aoff[i]];
#pragma unroll
        for (int j = 0; j < 4; ++j) {
            b1[j] = *(const bf16x8*)&ldsB1[boff[j]];
            b2[j] = *(const bf16x8*)&ldsB2[boff[j]];
        }
#pragma unroll
        for (int i = 0; i < 4; ++i)
#pragma unroll
            for (int j = 0; j < 4; ++j) {
                acc1[i][j] = __builtin_amdgcn_mfma_f32_16x16x32_bf16(a[i], b1[j], acc1[i][j], 0, 0, 0);
                acc2[i][j] = __builtin_amdgcn_mfma_f32_16x16x32_bf16(a[i], b2[j], acc2[i][j], 0, 0, 0);
            }
    }

    // epilogue: exact int accumulators, FP64 scale products, fp32 silu
    const double cw1 = scales[1];
    const double cw2 = scales[3];
#pragma unroll
    for (int i = 0; i < 4; ++i) {
#pragma unroll
        for (int v = 0; v < 4; ++v) {
            const int row = bm * 128 + wm * 64 + i * 16 + kg * 4 + v;
            const double c  = cx[row];
            const double s1 = c * cw1, s2 = c * cw2;
            float* hp = h + (size_t)row * H_FF + bn * 128 + wn * 64 + lm;
#pragma unroll
            for (int j = 0; j < 4; ++j) {
                float g  = (float)((double)acc1[i][j][v] * s1);
                float u  = (float)((double)acc2[i][j][v] * s2);
                float sg = g / (1.0f + expf(-g));   // silu
                hp[j * 16] = sg * u;
            }
        }
    }
}

// ---------------- GEMM3: q_h (ushort rows, stride 2*H_FF overlay) x t_w3 -> fp32 out ------
__global__ void __launch_bounds__(256) gemm3_kernel(
    const unsigned short* __restrict__ qh,
    const unsigned short* __restrict__ tw3,
    const double* __restrict__ ch,
    const double* __restrict__ scales,
    float* __restrict__ out)
{
    __shared__ unsigned short ldsA[128 * 32];
    __shared__ unsigned short ldsB[128 * 32];

    const int t  = threadIdx.x;
    const int bn = blockIdx.x;
    const int bm = blockIdx.y;

    const int srow = t >> 2;
    const int scol = (t & 3) << 3;
    const size_t qh_stride = (size_t)2 * H_FF;   // ushorts per token row (fp32 overlay)
    const unsigned short* gA = qh  + (size_t)(bm * 128 + srow) * qh_stride + scol;
    const unsigned short* gB = tw3 + (size_t)(bn * 128 + srow) * H_FF + scol;
    const size_t rstepA = (size_t)64 * qh_stride;
    const size_t rstepB = (size_t)64 * H_FF;

    unsigned short* lA0 = &ldsA[t * 8];
    unsigned short* lA1 = &ldsA[(t + 256) * 8];
    unsigned short* lB0 = &ldsB[t * 8];
    unsigned short* lB1 = &ldsB[(t + 256) * 8];

    const int lane = t & 63;
    const int wv = t >> 6;
    const int wm = wv & 1;
    const int wn = wv >> 1;
    const int lm = lane & 15;
    const int kg = lane >> 4;

    int aoff[4], boff[4];
#pragma unroll
    for (int i = 0; i < 4; ++i) aoff[i] = (wm * 64 + i * 16 + lm) * 32 + kg * 8;
#pragma unroll
    for (int j = 0; j < 4; ++j) boff[j] = (wn * 64 + j * 16 + lm) * 32 + kg * 8;

    const f32x4 fzero = {0.f, 0.f, 0.f, 0.f};
    f32x4 acc[4][4];
#pragma unroll
    for (int i = 0; i < 4; ++i)
#pragma unroll
        for (int j = 0; j < 4; ++j) acc[i][j] = fzero;

    for (int kt = 0; kt < H_FF / 32; ++kt) {
        __syncthreads();
        const int go = kt * 32;
        async16(gA + go, lA0); async16(gA + rstepA + go, lA1);
        async16(gB + go, lB0); async16(gB + rstepB + go, lB1);
        __syncthreads();

        bf16x8 a[4], b[4];
#pragma unroll
        for (int i = 0; i < 4; ++i) a[i] = *(const bf16x8*)&ldsA[aoff[i]];
#pragma unroll
        for (int j = 0; j < 4; ++j) b[j] = *(const bf16x8*)&ldsB[boff[j]];
#pragma unroll
        for (int i = 0; i < 4; ++i)
#pragma unroll
            for (int j = 0; j < 4; ++j)
                acc[i][j] = __builtin_amdgcn_mfma_f32_16x16x32_bf16(a[i], b[j], acc[i][j], 0, 0, 0);
    }

    const double cw3 = scales[5];
#pragma unroll
    for (int i = 0; i < 4; ++i) {
#pragma unroll
        for (int v = 0; v < 4; ++v) {
            const int row = bm * 128 + wm * 64 + i * 16 + kg * 4 + v;
            const double sc = ch[row] * cw3;
            float* op = out + (size_t)row * D_IN + bn * 128 + wn * 64 + lm;
#pragma unroll
            for (int j = 0; j < 4; ++j) op[j * 16] = (float)((double)acc[i][j][v] * sc);
        }
    }
}

// ---------------- launch ----------------
extern "C" void kernel_launch(void* const* d_in, const int* in_sizes, int n_in,
                              void* d_out, int out_size, void* d_ws, size_t ws_size,
                              hipStream_t stream) {
    const float* x  = (const float*)d_in[0];
    const float* w1 = (const float*)d_in[1];
    const float* w2 = (const float*)d_in[2];
    const float* w3 = (const float*)d_in[3];

    char* ws = (char*)d_ws;
    // workspace layout (bytes, 256-aligned); total = 505,701,376
    double*         scales = (double*)(ws + 0);          // 6 d
    double*         parts  = (double*)(ws + 256);        // 3*1024 d = 24576 B
    double*         cx     = (double*)(ws + 25088);      // 16384 d = 131072 B
    double*         ch     = (double*)(ws + 156416);     // 16384 d = 131072 B
    unsigned short* tw1    = (unsigned short*)(ws + 287744);     // 23,068,672 B
    unsigned short* tw2    = (unsigned short*)(ws + 23356416);   // 23,068,672 B
    unsigned short* tw3    = (unsigned short*)(ws + 46425088);   // 23,068,672 B
    float*          hb     = (float*)(ws + 69493760);            // 369,098,752 B (qh overlays in-place)
    unsigned short* qx     = (unsigned short*)(ws + 438592512);  // 67,108,864 B

    absum_partial<<<1024, 256, 0, stream>>>((const float4*)w1, NW / 4, parts);
    absum_partial<<<1024, 256, 0, stream>>>((const float4*)w2, NW / 4, parts + 1024);
    absum_partial<<<1024, 256, 0, stream>>>((const float4*)w3, NW / 4, parts + 2048);
    finalize_scales<<<1, 64, 0, stream>>>(parts, scales, 1024, 1.0 / (double)NW);
    quant_w_kernel<<<2048, 256, 0, stream>>>((const float4*)w1, (ushort4*)tw1, scales, 0, NW / 4);
    quant_w_kernel<<<2048, 256, 0, stream>>>((const float4*)w2, (ushort4*)tw2, scales, 1, NW / 4);
    quant_w_kernel<<<2048, 256, 0, stream>>>((const float4*)w3, (ushort4*)tw3, scales, 2, NW / 4);
    quant_x_kernel<<<M_TOK, 256, 0, stream>>>(x, qx, cx);
    gemm12_kernel<<<dim3(H_FF / 128, M_TOK / 128), 256, 0, stream>>>(qx, tw1, tw2, cx, scales, hb);
    quant_h_kernel<<<M_TOK, 256, 0, stream>>>(hb, ch);
    gemm3_kernel<<<dim3(D_IN / 128, M_TOK / 128), 256, 0, stream>>>((const unsigned short*)hb,
                                                                    tw3, ch, scales,
                                                                    (float*)d_out);
}